// Round 1
// baseline (163.510 us; speedup 1.0000x reference)
//
#include <hip/hip_runtime.h>
#include <math.h>

// SystemsOfSprings, round 2: one thread per NODE-PAIR, two pairs per thread.
//
// Round-1 (1 node/thread) sat at 42 us with VALUBusy 33%, HBM 34% of peak,
// zero conflicts -- latency/MLP-bound, not BW-bound. Fixes here:
//  * 4x memory-level parallelism: each thread owns nodes {2g,2g+1} of pair g
//    AND pair g+T (96 B of loads in flight per lane vs 24 B).
//  * Intra-pair edge (xor-distance 1, L=4.0) is register-local: computed once,
//    applied antisymmetrically -- no shuffle at all.
//  * Cross-pair edges (d=2 -> L=sqrt(18.25), d=3 -> L=1.5) need only a lane^1
//    exchange: emitted as DPP quad_perm [1,0,3,2] (VALU pipe, no ds_swizzle,
//    no lgkmcnt in the dependency chain).
//  * rsqrtf (v_rsq_f32) replaces sqrt + precise divide (tolerance is 7.8e-3).
//  * Non-temporal dwordx4 stores: out is write-only; keep L2/L3 for x,u.
//
// Physics per node n: a_n = -(p_n - t_n) - 2 v_n - sum_d (r_d - L_d) * e_d
// (goal force collapses analytically; atan2(0,0)=0 convention -> c=1,s=0).

#define TS 0.05f
#define L9 4.2720018727f  // sqrt(4^2 + 1.5^2) = sqrt(18.25)

typedef float f4v __attribute__((ext_vector_type(4)));

__device__ __forceinline__ float dpp_xor1(float v) {
    // quad_perm [1,0,3,2] == shfl_xor(.,1); row_mask/bank_mask full, bound_ctrl=1.
    return __int_as_float(__builtin_amdgcn_update_dpp(
        0, __float_as_int(v), 0xB1, 0xF, 0xF, true));
}

__device__ __forceinline__ void edge_acc(float dx, float dy, float L,
                                         float& ax, float& ay) {
    float d2   = dx * dx + dy * dy;
    bool  nz   = d2 > 0.f;
    float invr = nz ? rsqrtf(d2) : 0.f;
    float r    = d2 * invr;             // sqrt(d2); 0 when d2==0
    float c    = nz ? dx * invr : 1.f;  // atan2(0,0)=0 -> cos=1
    float sn   = dy * invr;             //              -> sin=0
    float Fk   = r - L;
    ax -= Fk * c;
    ay -= Fk * sn;
}

// One pair = nodes (2p, 2p+1) of some system. parity = p&1:
//   parity 0 -> nodes 0,1, targets (2,2) / (-2,2)
//   parity 1 -> nodes 2,3, targets (-2,-2) / (2,-2)
__device__ __forceinline__ void do_pair(int parity,
                                        float4 a, float4 b, float4 uc,
                                        float4& ra, float4& rb) {
    float xtA = parity ? -2.f : 2.f;
    float ytA = xtA;          // (2,2) or (-2,-2)
    float xtB = -xtA;
    float ytB = ytA;          // (-2,2) or (2,-2)

    // Goal force, analytically collapsed: a = -(p - t) - 2 v
    float axA = -(a.x - xtA) - 2.f * a.z;
    float ayA = -(a.y - ytA) - 2.f * a.w;
    float axB = -(b.x - xtB) - 2.f * b.z;
    float ayB = -(b.y - ytB) - 2.f * b.w;

    // Intra-pair edge: d=1, L=4.0, register-local, antisymmetric (A==EDGE_I).
    {
        float dx = a.x - b.x, dy = a.y - b.y;
        float d2   = dx * dx + dy * dy;
        bool  nz   = d2 > 0.f;
        float invr = nz ? rsqrtf(d2) : 0.f;
        float r    = d2 * invr;
        float c    = nz ? dx * invr : 1.f;
        float sn   = dy * invr;
        float Fk   = r - 4.0f;
        float fx = Fk * c, fy = Fk * sn;
        axA -= fx; ayA -= fy;
        axB += fx; ayB += fy;
    }

    // Partner pair (same system, other half) lives in lane^1.
    float pxA2 = dpp_xor1(a.x), pyA2 = dpp_xor1(a.y);
    float pxB2 = dpp_xor1(b.x), pyB2 = dpp_xor1(b.y);

    edge_acc(a.x - pxA2, a.y - pyA2, L9,   axA, ayA);  // A--A' : d=2
    edge_acc(a.x - pxB2, a.y - pyB2, 1.5f, axA, ayA);  // A--B' : d=3
    edge_acc(b.x - pxB2, b.y - pyB2, L9,   axB, ayB);  // B--B' : d=2
    edge_acc(b.x - pxA2, b.y - pyA2, 1.5f, axB, ayB);  // B--A' : d=3

    ra.x = a.x + TS * a.z;
    ra.y = a.y + TS * a.w;
    ra.z = a.z + TS * (axA + uc.x);
    ra.w = a.w + TS * (ayA + uc.y);
    rb.x = b.x + TS * b.z;
    rb.y = b.y + TS * b.w;
    rb.z = b.z + TS * (axB + uc.z);
    rb.w = b.w + TS * (ayB + uc.w);
}

__device__ __forceinline__ void nt_store4(float4 v, float4* p) {
    f4v t = { v.x, v.y, v.z, v.w };
    __builtin_nontemporal_store(t, reinterpret_cast<f4v*>(p));
}

__global__ __launch_bounds__(256) void springs_pair2_kernel(
    const float* __restrict__ x,
    const float* __restrict__ u,
    float* __restrict__ out,
    int T)  // T = B systems; thread g handles pairs g and g+T (T even)
{
    int g = blockIdx.x * blockDim.x + threadIdx.x;
    if (g >= T) return;
    int h = g + T;

    const float4* x4 = reinterpret_cast<const float4*>(x);
    const float4* u4 = reinterpret_cast<const float4*>(u);
    float4*       o4 = reinterpret_cast<float4*>(out);

    // Issue all six loads up front (independent -> all in flight together).
    float4 a0 = x4[2 * g];
    float4 b0 = x4[2 * g + 1];
    float4 a1 = x4[2 * h];
    float4 b1 = x4[2 * h + 1];
    float4 u0 = u4[g];
    float4 u1 = u4[h];

    float4 ra0, rb0, ra1, rb1;
    do_pair(g & 1, a0, b0, u0, ra0, rb0);
    do_pair(h & 1, a1, b1, u1, ra1, rb1);

    nt_store4(ra0, &o4[2 * g]);
    nt_store4(rb0, &o4[2 * g + 1]);
    nt_store4(ra1, &o4[2 * h]);
    nt_store4(rb1, &o4[2 * h + 1]);
}

extern "C" void kernel_launch(void* const* d_in, const int* in_sizes, int n_in,
                              void* d_out, int out_size, void* d_ws, size_t ws_size,
                              hipStream_t stream) {
    // Inputs (setup_inputs order): t (scalar), x (B*16 f32), u (B*8 f32),
    // w (16 f32, unused), xbar (16 f32, constant baked in).
    const float* x = (const float*)d_in[1];
    const float* u = (const float*)d_in[2];
    float* out = (float*)d_out;

    int T = in_sizes[1] / 16;  // B systems (in_sizes in f32 elements, 16/system)
    int block = 256;
    int grid = (T + block - 1) / block;
    springs_pair2_kernel<<<grid, block, 0, stream>>>(x, u, out, T);
}

// Round 2
// 157.238 us; speedup vs baseline: 1.0399x; 1.0399x over previous
//
#include <hip/hip_runtime.h>
#include <math.h>

// SystemsOfSprings, round 3: one node per LANE (round-1 layout), FOUR nodes
// per THREAD at stride S = N/4 (grid-strided slots, all accesses coalesced).
//
// Round-2 post-mortem: per-thread-contiguous float4 pairs made every wave
// memory op stride-32B (half of each cache line per instruction), and the
// non-temporal stores turned those partial lines into 1.56x HBM write
// amplification (WRITE_SIZE 64->102 MB), dur 42->59 us. nt-stores also gave
// zero FETCH benefit. Reverted both.
//
// Kept/new in round 3:
//  * 4x memory-level parallelism via 4 slots/thread at stride S (S%4==0, so
//    every slot preserves node = g&3 lane alignment; each aligned 4-lane
//    group holds nodes 0..3 of one system).
//  * Neighbor exchange via DPP quad_perm (xor1=0xB1, xor2=0x4E, xor3=0x1B):
//    1-cycle VALU ops -- no ds_swizzle, no lgkmcnt in the dependency chain
//    (round 1 had 6 of them per node).
//  * rsqrtf instead of sqrt + precise divide (tolerance is 7.8e-3; kills the
//    v_div_scale/fmas/fixup sequences).
//  * Plain dwordx4 stores (round 1 measured exactly 64 MB WRITE_SIZE).
//
// Physics per node n: a_n = -(p_n - t_n) - 2 v_n - sum_d (r_d - L_d) * e_d
// (goal force collapses analytically: cos(atan2(y,x)) = x/r; degenerate
// r==0 edge follows atan2(0,0)=0 -> c=1, s=0, same as round 1 which passed).

#define TS 0.05f
#define L9 4.2720018727f  // sqrt(4^2 + 1.5^2) = sqrt(18.25)

template <int CTRL>
__device__ __forceinline__ float dpp_qp(float v) {
    // quad_perm DPP: full row/bank masks, bound_ctrl=1. CTRL 0xB1 = [1,0,3,2]
    // (xor 1), 0x4E = [2,3,0,1] (xor 2), 0x1B = [3,2,1,0] (xor 3).
    return __int_as_float(__builtin_amdgcn_update_dpp(
        0, __float_as_int(v), CTRL, 0xF, 0xF, true));
}

__device__ __forceinline__ void edge_acc(float dx, float dy, float L,
                                         float& ax, float& ay) {
    float d2   = dx * dx + dy * dy;
    bool  nz   = d2 > 0.f;
    float invr = nz ? rsqrtf(d2) : 0.f;
    float r    = d2 * invr;             // sqrt(d2); 0 when d2==0
    float c    = nz ? dx * invr : 1.f;  // atan2(0,0)=0 -> cos=1
    float sn   = dy * invr;             //              -> sin=0
    float Fk   = r - L;
    ax -= Fk * c;
    ay -= Fk * sn;
}

__device__ __forceinline__ float4 node_step(float4 s, float2 uc,
                                            float xt, float yt) {
    // Goal force, analytically collapsed: a = -(p - t) - 2 v
    float ax = -(s.x - xt) - 2.f * s.z;
    float ay = -(s.y - yt) - 2.f * s.w;

    // Neighbors within the aligned 4-lane group (nodes 0..3 of this system).
    float qx1 = dpp_qp<0xB1>(s.x), qy1 = dpp_qp<0xB1>(s.y);
    float qx2 = dpp_qp<0x4E>(s.x), qy2 = dpp_qp<0x4E>(s.y);
    float qx3 = dpp_qp<0x1B>(s.x), qy3 = dpp_qp<0x1B>(s.y);

    edge_acc(s.x - qx1, s.y - qy1, 4.0f, ax, ay);  // xor-dist 1: (0,1),(2,3)
    edge_acc(s.x - qx2, s.y - qy2, L9,   ax, ay);  // xor-dist 2: (0,2),(1,3)
    edge_acc(s.x - qx3, s.y - qy3, 1.5f, ax, ay);  // xor-dist 3: (1,2),(3,0)

    float4 r;
    r.x = s.x + TS * s.z;
    r.y = s.y + TS * s.w;
    r.z = s.z + TS * (ax + uc.x);
    r.w = s.w + TS * (ay + uc.y);
    return r;
}

__global__ __launch_bounds__(256) void springs_node4_kernel(
    const float* __restrict__ x,
    const float* __restrict__ u,
    float* __restrict__ out,
    int S)  // S = N/4 threads; thread g handles nodes g, g+S, g+2S, g+3S
{
    int g = blockIdx.x * blockDim.x + threadIdx.x;
    if (g >= S) return;

    const float4* x4 = reinterpret_cast<const float4*>(x);
    const float2* u2 = reinterpret_cast<const float2*>(u);
    float4*       o4 = reinterpret_cast<float4*>(out);

    // All eight loads independent -> in flight together (96 B/lane).
    float4 s0 = x4[g];
    float4 s1 = x4[g + S];
    float4 s2 = x4[g + 2 * S];
    float4 s3 = x4[g + 3 * S];
    float2 c0 = u2[g];
    float2 c1 = u2[g + S];
    float2 c2 = u2[g + 2 * S];
    float2 c3 = u2[g + 3 * S];

    // S % 4 == 0, so node id is the same for all four slots.
    int node = g & 3;
    float xt = (node == 1 || node == 2) ? -2.f : 2.f;
    float yt = (node >= 2) ? -2.f : 2.f;

    o4[g]         = node_step(s0, c0, xt, yt);
    o4[g + S]     = node_step(s1, c1, xt, yt);
    o4[g + 2 * S] = node_step(s2, c2, xt, yt);
    o4[g + 3 * S] = node_step(s3, c3, xt, yt);
}

extern "C" void kernel_launch(void* const* d_in, const int* in_sizes, int n_in,
                              void* d_out, int out_size, void* d_ws, size_t ws_size,
                              hipStream_t stream) {
    // Inputs (setup_inputs order): t (scalar), x (B*16 f32), u (B*8 f32),
    // w (16 f32, unused), xbar (16 f32, constant baked in).
    const float* x = (const float*)d_in[1];
    const float* u = (const float*)d_in[2];
    float* out = (float*)d_out;

    int N = in_sizes[1] / 4;  // total nodes = B*4
    int S = N / 4;            // threads; stride between a thread's slots
    int block = 256;
    int grid = (S + block - 1) / block;
    springs_node4_kernel<<<grid, block, 0, stream>>>(x, u, out, S);
}

// Round 3
// 148.567 us; speedup vs baseline: 1.1006x; 1.0584x over previous
//
#include <hip/hip_runtime.h>
#include <math.h>

// SystemsOfSprings, round 4: round-1 node-per-lane layout, 4 nodes per thread
// unrolled BLOCK-LOCALLY (slots 256 apart, not N/4 apart).
//
// Evidence trail:
//  * r1 (1 node/thread): 42 us, WRITE exactly 64 MB, VALU 33%, HBM 34% --
//    latency-bound, nothing saturated.
//  * r2 (thread-contiguous pairs + nt stores): partial-line wave ops ->
//    WRITE 102 MB, 59 us.
//  * r3 (4 slots at stride N/4 = 16 MB): per-op coalescing perfect, DPP+rsqrt
//    dropped VALUBusy to 12%, but WRITE amplified to 85 MB and dur rose to
//    53 us. The 16 MB / 8 MB power-of-two stream separations alias to the
//    same L2/MALL sets (all index bits equal) -> write-path conflict thrash.
//  * => keep 4x MLP but make the four slots block-local: block owns 1024
//    consecutive nodes, thread t handles base+t+{0,256,512,768}. All twelve
//    streams of a block live in one 16 KB contiguous window: full lines,
//    same DRAM pages, no power-of-two set aliasing. Node parity is
//    preserved: (base + k*256 + t) & 3 == t & 3.
//
// Kept from r3 (verified correct, VALU-chain win): DPP quad_perm neighbor
// exchange (xor1=0xB1, xor2=0x4E, xor3=0x1B; 1-cycle VALU, no lgkmcnt) and
// rsqrtf (tolerance 7.8e-3; kills precise-divide sequences).
//
// Physics per node n: a_n = -(p_n - t_n) - 2 v_n - sum_d (r_d - L_d) * e_d
// (goal force collapsed analytically; r==0 edge: atan2(0,0)=0 -> c=1, s=0).

#define TS 0.05f
#define L9 4.2720018727f  // sqrt(4^2 + 1.5^2) = sqrt(18.25)

template <int CTRL>
__device__ __forceinline__ float dpp_qp(float v) {
    // quad_perm DPP: full row/bank masks, bound_ctrl=1. 0xB1=[1,0,3,2],
    // 0x4E=[2,3,0,1], 0x1B=[3,2,1,0].
    return __int_as_float(__builtin_amdgcn_update_dpp(
        0, __float_as_int(v), CTRL, 0xF, 0xF, true));
}

__device__ __forceinline__ void edge_acc(float dx, float dy, float L,
                                         float& ax, float& ay) {
    float d2   = dx * dx + dy * dy;
    bool  nz   = d2 > 0.f;
    float invr = nz ? rsqrtf(d2) : 0.f;
    float r    = d2 * invr;             // sqrt(d2); 0 when d2==0
    float c    = nz ? dx * invr : 1.f;  // atan2(0,0)=0 -> cos=1
    float sn   = dy * invr;             //              -> sin=0
    float Fk   = r - L;
    ax -= Fk * c;
    ay -= Fk * sn;
}

__device__ __forceinline__ float4 node_step(float4 s, float2 uc,
                                            float xt, float yt) {
    // Goal force, analytically collapsed: a = -(p - t) - 2 v
    float ax = -(s.x - xt) - 2.f * s.z;
    float ay = -(s.y - yt) - 2.f * s.w;

    // Neighbors: nodes 0..3 of this system live in the aligned 4-lane group.
    float qx1 = dpp_qp<0xB1>(s.x), qy1 = dpp_qp<0xB1>(s.y);
    float qx2 = dpp_qp<0x4E>(s.x), qy2 = dpp_qp<0x4E>(s.y);
    float qx3 = dpp_qp<0x1B>(s.x), qy3 = dpp_qp<0x1B>(s.y);

    edge_acc(s.x - qx1, s.y - qy1, 4.0f, ax, ay);  // xor 1: (0,1),(2,3)
    edge_acc(s.x - qx2, s.y - qy2, L9,   ax, ay);  // xor 2: (0,2),(1,3)
    edge_acc(s.x - qx3, s.y - qy3, 1.5f, ax, ay);  // xor 3: (1,2),(3,0)

    float4 r;
    r.x = s.x + TS * s.z;
    r.y = s.y + TS * s.w;
    r.z = s.z + TS * (ax + uc.x);
    r.w = s.w + TS * (ay + uc.y);
    return r;
}

__global__ __launch_bounds__(256) void springs_blk4_kernel(
    const float* __restrict__ x,
    const float* __restrict__ u,
    float* __restrict__ out,
    int N)  // N = total nodes = B*4
{
    int base = blockIdx.x * 1024 + threadIdx.x;  // block owns 1024 nodes

    const float4* x4 = reinterpret_cast<const float4*>(x);
    const float2* u2 = reinterpret_cast<const float2*>(u);
    float4*       o4 = reinterpret_cast<float4*>(out);

    // 256 % 4 == 0 -> node id identical across the four slots.
    int node = threadIdx.x & 3;
    float xt = (node == 1 || node == 2) ? -2.f : 2.f;
    float yt = (node >= 2) ? -2.f : 2.f;

    if (blockIdx.x * 1024 + 1023 < N) {
        // Full block: all eight loads issued back-to-back (96 B/lane MLP),
        // all streams within one 16 KB contiguous window.
        float4 s0 = x4[base];
        float4 s1 = x4[base + 256];
        float4 s2 = x4[base + 512];
        float4 s3 = x4[base + 768];
        float2 c0 = u2[base];
        float2 c1 = u2[base + 256];
        float2 c2 = u2[base + 512];
        float2 c3 = u2[base + 768];

        o4[base]       = node_step(s0, c0, xt, yt);
        o4[base + 256] = node_step(s1, c1, xt, yt);
        o4[base + 512] = node_step(s2, c2, xt, yt);
        o4[base + 768] = node_step(s3, c3, xt, yt);
    } else {
        // Tail block (not hit at B=2^20, but keep it correct).
#pragma unroll
        for (int k = 0; k < 4; ++k) {
            int i = base + k * 256;
            if (i < N) {
                o4[i] = node_step(x4[i], u2[i], xt, yt);
            }
        }
    }
}

extern "C" void kernel_launch(void* const* d_in, const int* in_sizes, int n_in,
                              void* d_out, int out_size, void* d_ws, size_t ws_size,
                              hipStream_t stream) {
    // Inputs (setup_inputs order): t (scalar), x (B*16 f32), u (B*8 f32),
    // w (16 f32, unused), xbar (16 f32, constant baked in).
    const float* x = (const float*)d_in[1];
    const float* u = (const float*)d_in[2];
    float* out = (float*)d_out;

    int N = in_sizes[1] / 4;  // total nodes = B*4
    int block = 256;
    int grid = (N + 1023) / 1024;
    springs_blk4_kernel<<<grid, block, 0, stream>>>(x, u, out, N);
}